// Round 9
// baseline (265.280 us; speedup 1.0000x reference)
//
#include <hip/hip_runtime.h>
#include <cmath>

#define B_ 32
#define S_ 4096
#define E_ 512
#define H_ 1024
#define V_ 50257
#define WPITCH 50304          // padded w row pitch
#define CHA 64                // vocab rows per scorew block
#define NBA 786               // ceil(V_/CHA)
#define CHB 96                // vocab rows per wsum block
#define NCH 524               // ceil(V_/CHB)
#define NG 17                 // ceil(NCH/32) combine stage-1 groups

// ---------------------------------------------------------------------------
// Kernel 1: v_t[b,e] = tanhf(dot(h[b,:], W[e,:]) + bias[e])  (proven)
// ---------------------------------------------------------------------------
__global__ __launch_bounds__(256) void vt_kernel(const float* __restrict__ h,
                                                 const float* __restrict__ W,
                                                 const float* __restrict__ bias,
                                                 float* __restrict__ vt) {
    int wid  = threadIdx.x >> 6;
    int lane = threadIdx.x & 63;
    int out  = blockIdx.x * 4 + wid;
    int b    = out >> 9;
    int e    = out & (E_ - 1);
    const float* hrow = h + b * H_;
    const float* wrow = W + (size_t)e * H_;
    int base = lane * 16;
    float acc = 0.f;
#pragma unroll
    for (int j = 0; j < 4; ++j) {
        float4 hv = *reinterpret_cast<const float4*>(hrow + base + j * 4);
        float4 wv = *reinterpret_cast<const float4*>(wrow + base + j * 4);
        acc += hv.x * wv.x + hv.y * wv.y + hv.z * wv.z + hv.w * wv.w;
    }
#pragma unroll
    for (int off = 32; off > 0; off >>= 1) acc += __shfl_xor(acc, off, 64);
    if (lane == 0) vt[out] = tanhf(acc + bias[e]);
}

// ---------------------------------------------------------------------------
// Kernel 2: histogram counts[b][v] += 1
// ---------------------------------------------------------------------------
__global__ __launch_bounds__(256) void hist_kernel(const int* __restrict__ mems,
                                                   int* __restrict__ counts) {
    int i = blockIdx.x * 256 + threadIdx.x;
    int b = i >> 12;
    atomicAdd(counts + (size_t)b * V_ + mems[i], 1);
}

// ---------------------------------------------------------------------------
// Kernel 3 (pass A): w[b][v] = counts * exp(dot(emb[v], vt[b])) + l-partials.
// 64v x 32b tile, 256 thr, thread = 4v x 2b with STRIDED rows (vh+16i):
// row-group stride 17 coprime 8 -> e-reads hit all 8 bank groups at 2-way
// (free). Per k4: 4 e-reads + 2 t-reads vs 32 FMA -> VALU-parity per CU.
// ---------------------------------------------------------------------------
#define DOT4(t, e) ((t).x*(e).x + (t).y*(e).y + (t).z*(e).z + (t).w*(e).w)

__global__ __launch_bounds__(256) void scorew_kernel(const float* __restrict__ emb,
                                                     const float* __restrict__ vt,
                                                     const int* __restrict__ counts,
                                                     float* __restrict__ w,
                                                     float* __restrict__ lpart) {
    const int tid   = threadIdx.x;
    const int vbase = blockIdx.x * CHA;
    const int vh = tid & 15;          // 0..15
    const int bh = tid >> 4;          // 0..15
    const int b0 = bh * 2;

    __shared__ float4 s_e[CHA][17];
    __shared__ float4 s_v[32][17];
    __shared__ float  s_lp[32];

    float acc[4][2];
#pragma unroll
    for (int i = 0; i < 4; ++i) { acc[i][0] = 0.f; acc[i][1] = 0.f; }

    const int sr = tid >> 4;          // staging row base 0..15
    const int sc = tid & 15;          // staging col 0..15

    int ge0 = vbase + sr;      if (ge0 >= V_) ge0 = V_ - 1;
    int ge1 = vbase + sr + 16; if (ge1 >= V_) ge1 = V_ - 1;
    int ge2 = vbase + sr + 32; if (ge2 >= V_) ge2 = V_ - 1;
    int ge3 = vbase + sr + 48; if (ge3 >= V_) ge3 = V_ - 1;

    float4 pe0, pe1, pe2, pe3, pv0, pv1;

    // prologue: stage k-tile 0
    pe0 = *reinterpret_cast<const float4*>(emb + (size_t)ge0 * E_ + sc * 4);
    pe1 = *reinterpret_cast<const float4*>(emb + (size_t)ge1 * E_ + sc * 4);
    pe2 = *reinterpret_cast<const float4*>(emb + (size_t)ge2 * E_ + sc * 4);
    pe3 = *reinterpret_cast<const float4*>(emb + (size_t)ge3 * E_ + sc * 4);
    pv0 = *reinterpret_cast<const float4*>(vt + sr * E_ + sc * 4);
    pv1 = *reinterpret_cast<const float4*>(vt + (sr + 16) * E_ + sc * 4);
    s_e[sr][sc] = pe0; s_e[sr + 16][sc] = pe1;
    s_e[sr + 32][sc] = pe2; s_e[sr + 48][sc] = pe3;
    s_v[sr][sc] = pv0; s_v[sr + 16][sc] = pv1;
    __syncthreads();

    for (int kt = 0; kt < E_; kt += 64) {
        bool more = (kt + 64) < E_;
        if (more) {
            int ko = kt + 64;
            pe0 = *reinterpret_cast<const float4*>(emb + (size_t)ge0 * E_ + ko + sc * 4);
            pe1 = *reinterpret_cast<const float4*>(emb + (size_t)ge1 * E_ + ko + sc * 4);
            pe2 = *reinterpret_cast<const float4*>(emb + (size_t)ge2 * E_ + ko + sc * 4);
            pe3 = *reinterpret_cast<const float4*>(emb + (size_t)ge3 * E_ + ko + sc * 4);
            pv0 = *reinterpret_cast<const float4*>(vt + sr * E_ + ko + sc * 4);
            pv1 = *reinterpret_cast<const float4*>(vt + (sr + 16) * E_ + ko + sc * 4);
        }
#pragma unroll
        for (int k4 = 0; k4 < 16; ++k4) {
            float4 t0 = s_v[b0][k4];
            float4 t1 = s_v[b0 + 1][k4];
            float4 e0 = s_e[vh][k4];
            float4 e1 = s_e[vh + 16][k4];
            float4 e2 = s_e[vh + 32][k4];
            float4 e3 = s_e[vh + 48][k4];
            acc[0][0] += DOT4(e0, t0); acc[0][1] += DOT4(e0, t1);
            acc[1][0] += DOT4(e1, t0); acc[1][1] += DOT4(e1, t1);
            acc[2][0] += DOT4(e2, t0); acc[2][1] += DOT4(e2, t1);
            acc[3][0] += DOT4(e3, t0); acc[3][1] += DOT4(e3, t1);
        }
        if (more) {
            __syncthreads();
            s_e[sr][sc] = pe0; s_e[sr + 16][sc] = pe1;
            s_e[sr + 32][sc] = pe2; s_e[sr + 48][sc] = pe3;
            s_v[sr][sc] = pv0; s_v[sr + 16][sc] = pv1;
            __syncthreads();
        }
    }

    // epilogue: w = c*exp(score); l-partials
    float lsum0 = 0.f, lsum1 = 0.f;
#pragma unroll
    for (int i = 0; i < 4; ++i) {
        int v = vbase + vh + 16 * i;
        if (v < V_) {
            int c0 = counts[(size_t)b0 * V_ + v];
            int c1 = counts[(size_t)(b0 + 1) * V_ + v];
            float w0 = c0 ? (float)c0 * __expf(acc[i][0]) : 0.f;
            float w1 = c1 ? (float)c1 * __expf(acc[i][1]) : 0.f;
            w[(size_t)b0 * WPITCH + v] = w0;
            w[(size_t)(b0 + 1) * WPITCH + v] = w1;
            lsum0 += w0; lsum1 += w1;
        }
    }
#pragma unroll
    for (int off = 1; off < 16; off <<= 1) {
        lsum0 += __shfl_xor(lsum0, off, 16);
        lsum1 += __shfl_xor(lsum1, off, 16);
    }
    if (vh == 0) { s_lp[b0] = lsum0; s_lp[b0 + 1] = lsum1; }
    __syncthreads();
    if (tid < 32) lpart[(size_t)blockIdx.x * 32 + tid] = s_lp[tid];
}

// ---------------------------------------------------------------------------
// Kernel 4: inv_l[b] = 1 / sum over blocks of lpart
// ---------------------------------------------------------------------------
__global__ __launch_bounds__(256) void invl_kernel(const float* __restrict__ lpart,
                                                   float* __restrict__ inv_l) {
    int b = threadIdx.x & 31;
    int g = threadIdx.x >> 5;
    float s = 0.f;
    for (int blk = g; blk < NBA; blk += 8)
        s += lpart[(size_t)blk * 32 + b];
    __shared__ float red[8][32];
    red[g][b] = s;
    __syncthreads();
    if (threadIdx.x < 32) {
        float t = 0.f;
#pragma unroll
        for (int gg = 0; gg < 8; ++gg) t += red[gg][threadIdx.x];
        inv_l[threadIdx.x] = 1.f / t;
    }
}

// ---------------------------------------------------------------------------
// Kernel 5 (pass B): partial[ch][b][e] += w[b][v]*emb[v][e] over 96 rows.
// 512 thr = full e-row. Named X/Y 8-deep ev software pipeline keeps 16 rows
// in flight (forces VGPR headroom, overlaps HBM latency with 256-FMA blocks).
// ---------------------------------------------------------------------------
#define LOADE(RR, R0, R1, R2, R3, R4, R5, R6, R7)                            \
    {                                                                        \
        int vb = rbeg + (RR);                                                \
        R0 = emb[(size_t)((vb + 0 < V_) ? vb + 0 : V_ - 1) * E_ + e];        \
        R1 = emb[(size_t)((vb + 1 < V_) ? vb + 1 : V_ - 1) * E_ + e];        \
        R2 = emb[(size_t)((vb + 2 < V_) ? vb + 2 : V_ - 1) * E_ + e];        \
        R3 = emb[(size_t)((vb + 3 < V_) ? vb + 3 : V_ - 1) * E_ + e];        \
        R4 = emb[(size_t)((vb + 4 < V_) ? vb + 4 : V_ - 1) * E_ + e];        \
        R5 = emb[(size_t)((vb + 5 < V_) ? vb + 5 : V_ - 1) * E_ + e];        \
        R6 = emb[(size_t)((vb + 6 < V_) ? vb + 6 : V_ - 1) * E_ + e];        \
        R7 = emb[(size_t)((vb + 7 < V_) ? vb + 7 : V_ - 1) * E_ + e];        \
    }

#define FMAB(RR, R0, R1, R2, R3, R4, R5, R6, R7)                             \
    {                                                                        \
        _Pragma("unroll")                                                    \
        for (int b = 0; b < 32; ++b) {                                       \
            float4 wa = *reinterpret_cast<const float4*>(&s_w[b][(RR)]);     \
            float4 wb = *reinterpret_cast<const float4*>(&s_w[b][(RR) + 4]); \
            acc[b] += wa.x * R0 + wa.y * R1 + wa.z * R2 + wa.w * R3          \
                    + wb.x * R4 + wb.y * R5 + wb.z * R6 + wb.w * R7;         \
        }                                                                    \
    }

__global__ __launch_bounds__(512) void wsum_kernel(const float* __restrict__ emb,
                                                   const float* __restrict__ w,
                                                   float* __restrict__ partial) {
    int ch   = blockIdx.x;
    int rbeg = ch * CHB;
    int e    = threadIdx.x;

    __shared__ float s_w[32][CHB];
    // stage 32x96 weights, coalesced (6 f32/thread)
#pragma unroll
    for (int j = 0; j < 6; ++j) {
        int idx = threadIdx.x + j * 512;       // 0..3071
        int b   = idx / CHB;
        int r   = idx - b * CHB;
        int v   = rbeg + r;
        s_w[b][r] = (v < V_) ? w[(size_t)b * WPITCH + v] : 0.f;
    }
    __syncthreads();

    float acc[32];
#pragma unroll
    for (int b = 0; b < 32; ++b) acc[b] = 0.f;

    float x0, x1, x2, x3, x4, x5, x6, x7;
    float y0, y1, y2, y3, y4, y5, y6, y7;

    LOADE(0, x0, x1, x2, x3, x4, x5, x6, x7);
#pragma unroll
    for (int rr = 0; rr < CHB; rr += 16) {
        LOADE(rr + 8, y0, y1, y2, y3, y4, y5, y6, y7);
        FMAB(rr, x0, x1, x2, x3, x4, x5, x6, x7);
        if (rr + 16 < CHB)
            LOADE(rr + 16, x0, x1, x2, x3, x4, x5, x6, x7);
        FMAB(rr + 8, y0, y1, y2, y3, y4, y5, y6, y7);
    }

#pragma unroll
    for (int b = 0; b < 32; ++b)
        partial[((size_t)ch * 32 + b) * E_ + e] = acc[b];
}

// ---------------------------------------------------------------------------
// Kernel 6/7: two-stage deterministic combine (+ normalize by inv_l)
// ---------------------------------------------------------------------------
__global__ __launch_bounds__(512) void comb1_kernel(const float* __restrict__ partial,
                                                    float* __restrict__ tmp) {
    int g = blockIdx.x >> 5;          // 0..NG-1
    int b = blockIdx.x & 31;
    int e = threadIdx.x;
    float s = 0.f;
#pragma unroll
    for (int i = 0; i < 32; ++i) {
        int c = g * 32 + i;
        if (c < NCH) s += partial[((size_t)c * 32 + b) * E_ + e];
    }
    tmp[((size_t)g * 32 + b) * E_ + e] = s;
}

__global__ __launch_bounds__(512) void comb2_kernel(const float* __restrict__ tmp,
                                                    const float* __restrict__ inv_l,
                                                    float* __restrict__ out) {
    int b = blockIdx.x;
    int e = threadIdx.x;
    float s = 0.f;
#pragma unroll
    for (int g = 0; g < NG; ++g)
        s += tmp[((size_t)g * 32 + b) * E_ + e];
    out[(size_t)b * E_ + e] = s * inv_l[b];
}

extern "C" void kernel_launch(void* const* d_in, const int* in_sizes, int n_in,
                              void* d_out, int out_size, void* d_ws, size_t ws_size,
                              hipStream_t stream) {
    const float* h    = (const float*)d_in[0];   // [B,H]
    const int*   mems = (const int*)d_in[1];     // [B,S]
    const float* emb  = (const float*)d_in[2];   // [V,E]
    const float* W    = (const float*)d_in[3];   // [E,H]
    const float* bias = (const float*)d_in[4];   // [E]
    float* out = (float*)d_out;                  // [B,1,E]

    float* ws = (float*)d_ws;
    const size_t CNT = (size_t)B_ * V_;
    float* vt      = ws;                                      // 16384
    int*   counts  = (int*)(ws + 16384);                      // CNT
    float* lpart   = ws + 16384 + CNT;                        // NBA*32
    float* inv_l   = lpart + (size_t)NBA * 32;                // 32
    float* w       = inv_l + 32;                              // 32*WPITCH
    float* partial = w + (size_t)32 * WPITCH;                 // NCH*32*512
    float* tmp     = partial + (size_t)NCH * 32 * E_;         // NG*32*512

    hipMemsetAsync(counts, 0, CNT * sizeof(int), stream);

    hipLaunchKernelGGL(vt_kernel, dim3(B_ * E_ / 4), dim3(256), 0, stream,
                       h, W, bias, vt);
    hipLaunchKernelGGL(hist_kernel, dim3(B_ * S_ / 256), dim3(256), 0, stream,
                       mems, counts);
    hipLaunchKernelGGL(scorew_kernel, dim3(NBA), dim3(256), 0, stream,
                       emb, vt, counts, w, lpart);
    hipLaunchKernelGGL(invl_kernel, dim3(1), dim3(256), 0, stream,
                       lpart, inv_l);
    hipLaunchKernelGGL(wsum_kernel, dim3(NCH), dim3(512), 0, stream,
                       emb, w, partial);
    hipLaunchKernelGGL(comb1_kernel, dim3(NG * 32), dim3(512), 0, stream,
                       partial, tmp);
    hipLaunchKernelGGL(comb2_kernel, dim3(32), dim3(512), 0, stream,
                       tmp, inv_l, out);
}